// Round 7
// baseline (205.583 us; speedup 1.0000x reference)
//
#include <hip/hip_runtime.h>

// PSU LIF: V_t = b*V_{t-1} + x_t ; R_t = b*R_{t-1} + sigmoid(V_t)
// out0 = (V - R - 1 > 0), out1 = V.  x:[16,1024,1024] f32, beta:[1024] f32.
//
// Round-7: barrier-free 3-kernel pipeline (anti-convoy).
//   r3-r6 evidence: kernel pinned at 62-72us (2.2x the 29us per-CU BW floor)
//   regardless of occupancy/vector-width/VALU cost. Surviving theory: the
//   in-block phase structure (load-burst -> barrier -> serial carry -> mixed
//   pass -> barrier -> ...) convoys all resident waves, idling memory during
//   VALU/LDS phases. Fix: three homogeneous streaming kernels with NO
//   barriers, NO LDS, block-uniform carry loops:
//     K1: per-(b,tc,h) local V chunk-sums over TC=32 steps -> ws[0:2MB]
//     K3: prologue = V carry scan from ws (<=31 fma4, block-uniform);
//         rescan x (LLC-warm) seeded exactly, write V, local R-sums -> ws[2MB:]
//     K4: prologue = R carry scan; re-read V (LLC-warm), rescan R, NT-store spike
//   Thread = 4 consecutive h (f4); block = 256 thr covers all 1024 h of one
//   (b, t-chunk) slab -> every wave-instr is 1KB contiguous (like the 6.7TB/s
//   fills). grid = 16b x 32tc = 512 blocks.
// HBM optimum unchanged: read x 67MB, write V+spike 134MB (+4MB ws).

#define BB 16
#define TT 1024
#define HH 1024
#define TC 32               // timesteps per chunk
#define NC 32               // chunks = TT/TC
#define STRD4 (HH / 4)      // f4 elements per timestep row

typedef float f4 __attribute__((ext_vector_type(4)));

__device__ __forceinline__ f4 fma4(f4 a, f4 b, f4 c) {
    f4 r;
#pragma unroll
    for (int k = 0; k < 4; ++k) r[k] = fmaf(a[k], b[k], c[k]);
    return r;
}

__device__ __forceinline__ f4 load_beta(const float* beta, int h0) {
    f4 bf = *reinterpret_cast<const f4*>(beta + h0);
#pragma unroll
    for (int k = 0; k < 4; ++k) bf[k] = fminf(fmaxf(bf[k], 0.0f), 1.0f);
    return bf;
}

// ---- K1: local V chunk sums (pure streaming read, tiny write) ----
__global__ __launch_bounds__(256) void k_vsum(const float* __restrict__ x,
                                              const float* __restrict__ beta,
                                              float* __restrict__ S) {
    const int blk = blockIdx.x;
    const int b = blk >> 5, tc = blk & 31;
    const int h0 = threadIdx.x << 2;
    const f4 bf = load_beta(beta, h0);

    const f4* __restrict__ xv =
        reinterpret_cast<const f4*>(x + ((size_t)b * TT + (size_t)tc * TC) * HH + h0);
    f4 V = (f4)0.0f;
#pragma unroll
    for (int t = 0; t < TC; ++t) V = fma4(bf, V, xv[(size_t)t * STRD4]);
    *reinterpret_cast<f4*>(S + ((size_t)b * NC + tc) * HH + h0) = V;
}

// ---- K3: V carry + exact V rescan + R chunk sums ----
__global__ __launch_bounds__(256) void k_vpass(const float* __restrict__ x,
                                               const float* __restrict__ beta,
                                               const float* __restrict__ S,
                                               float* __restrict__ Rsum,
                                               float* __restrict__ out_v) {
    const int blk = blockIdx.x;
    const int b = blk >> 5, tc = blk & 31;
    const int h0 = threadIdx.x << 2;
    const f4 bf = load_beta(beta, h0);
    f4 A = bf;                               // bf^TC via 5 squarings
#pragma unroll
    for (int k = 0; k < 5; ++k) A *= A;

    // carry: Vstart(tc) = sum_{j<tc} A^(tc-1-j) * S_j  (tc uniform per block)
    f4 Vs = (f4)0.0f;
    for (int j = 0; j < tc; ++j)
        Vs = fma4(A, Vs, *reinterpret_cast<const f4*>(S + ((size_t)b * NC + j) * HH + h0));

    const size_t base = ((size_t)b * TT + (size_t)tc * TC) * HH + h0;
    const f4* __restrict__ xv = reinterpret_cast<const f4*>(x + base);
    f4* __restrict__ vv = reinterpret_cast<f4*>(out_v + base);

    f4 V = Vs, R = (f4)0.0f;
#pragma unroll
    for (int t = 0; t < TC; ++t) {
        V = fma4(bf, V, xv[(size_t)t * STRD4]);      // LLC-warm re-read
        vv[(size_t)t * STRD4] = V;
        f4 sg;
#pragma unroll
        for (int k = 0; k < 4; ++k) sg[k] = __builtin_amdgcn_rcpf(1.0f + __expf(-V[k]));
        R = fma4(bf, R, sg);
    }
    *reinterpret_cast<f4*>(Rsum + ((size_t)b * NC + tc) * HH + h0) = R;
}

// ---- K4: R carry + exact R rescan + spike ----
__global__ __launch_bounds__(256) void k_spike(const float* __restrict__ beta,
                                               const float* __restrict__ Rsum,
                                               const float* __restrict__ out_v,
                                               float* __restrict__ out_s) {
    const int blk = blockIdx.x;
    const int b = blk >> 5, tc = blk & 31;
    const int h0 = threadIdx.x << 2;
    const f4 bf = load_beta(beta, h0);
    f4 A = bf;
#pragma unroll
    for (int k = 0; k < 5; ++k) A *= A;

    f4 Rs = (f4)0.0f;
    for (int j = 0; j < tc; ++j)
        Rs = fma4(A, Rs, *reinterpret_cast<const f4*>(Rsum + ((size_t)b * NC + j) * HH + h0));

    const size_t base = ((size_t)b * TT + (size_t)tc * TC) * HH + h0;
    const f4* __restrict__ vv = reinterpret_cast<const f4*>(out_v + base);
    f4* __restrict__ sv = reinterpret_cast<f4*>(out_s + base);

    f4 R = Rs;
#pragma unroll
    for (int t = 0; t < TC; ++t) {
        const f4 vf = vv[(size_t)t * STRD4];         // LLC-warm (K3 wrote it)
        f4 sg;
#pragma unroll
        for (int k = 0; k < 4; ++k) sg[k] = __builtin_amdgcn_rcpf(1.0f + __expf(-vf[k]));
        R = fma4(bf, R, sg);
        f4 sp;
#pragma unroll
        for (int k = 0; k < 4; ++k) sp[k] = (vf[k] - R[k] > 1.0f) ? 1.0f : 0.0f;
        __builtin_nontemporal_store(sp, sv + (size_t)t * STRD4);
    }
}

extern "C" void kernel_launch(void* const* d_in, const int* in_sizes, int n_in,
                              void* d_out, int out_size, void* d_ws, size_t ws_size,
                              hipStream_t stream) {
    const float* x = (const float*)d_in[0];
    const float* beta = (const float*)d_in[1];
    float* out = (float*)d_out;
    float* out_spike = out;                               // [16,1024,1024]
    float* out_v = out + (size_t)BB * TT * HH;            // [16,1024,1024]
    float* S = (float*)d_ws;                              // [16][32][1024] = 2 MB
    float* Rsum = S + (size_t)BB * NC * HH;               // [16][32][1024] = 2 MB

    const int grid = BB * NC;                             // 512 blocks
    k_vsum<<<grid, 256, 0, stream>>>(x, beta, S);
    k_vpass<<<grid, 256, 0, stream>>>(x, beta, S, Rsum, out_v);
    k_spike<<<grid, 256, 0, stream>>>(beta, Rsum, out_v, out_spike);
}